// Round 3
// baseline (209.387 us; speedup 1.0000x reference)
//
#include <hip/hip_runtime.h>
#include <hip/hip_bf16.h>

// Problem constants (match reference.py)
#define BB 64
#define SS 512
#define WW 400
#define DD 1024
#define D4 (DD / 4)        // 256 float4 per row
#define NWORDS (BB * WW)   // 25600

// Native vector type for nontemporal builtin (HIP float4 is rejected).
typedef float vfloat4 __attribute__((ext_vector_type(4)));

// Persistent grid-stride: 2048 blocks (8 per CU, all resident), each block
// processes ~12.5 words. Next word's offsets/mask are prefetched before the
// current word's span loop so the uniform-load latency is hidden behind the
// current word's loads/stores.
__global__ __launch_bounds__(256, 8) void bert_span_mean(
    const float* __restrict__ emb,     // [B, S, D]
    const int*   __restrict__ offs,    // [B, W, 2]
    const int*   __restrict__ mask,    // [B, W]
    float*       __restrict__ out)     // [B, W, D]
{
    const int t = threadIdx.x;                 // 0..255 -> float4 lane in D
    const int stride = (int)gridDim.x;
    const int2* __restrict__ offs2 = reinterpret_cast<const int2*>(offs);

    int i = (int)blockIdx.x;                   // current word index (block-uniform)
    int2 cur = offs2[i];
    int  m   = mask[i];

    while (true) {
        // Prefetch next word's metadata (independent of current word's data).
        const int inext = i + stride;
        int2 nxt = make_int2(0, 0);
        int  mn  = 0;
        if (inext < NWORDS) {
            nxt = offs2[inext];
            mn  = mask[inext];
        }

        const int b  = i / WW;
        const int st = cur.x;
        const int ed = cur.y;

        vfloat4 acc = (vfloat4)(0.f);
        if ((m != 0) && (ed > st)) {
            const vfloat4* src = reinterpret_cast<const vfloat4*>(
                emb + (size_t)b * SS * DD) + t;
            for (int s = st; s < ed; ++s) {
                vfloat4 v = src[(size_t)s * D4];
                acc += v;
            }
            const float inv = 1.0f / (float)(ed - st);
            acc *= inv;
        }

        // Streaming store: out has zero reuse; nt flag avoids L2 pollution.
        __builtin_nontemporal_store(acc,
            reinterpret_cast<vfloat4*>(out) + (size_t)i * D4 + t);

        if (inext >= NWORDS) break;
        i   = inext;
        cur = nxt;
        m   = mn;
    }
}

extern "C" void kernel_launch(void* const* d_in, const int* in_sizes, int n_in,
                              void* d_out, int out_size, void* d_ws, size_t ws_size,
                              hipStream_t stream) {
    const float* emb  = (const float*)d_in[0];
    const int*   offs = (const int*)d_in[1];
    const int*   mask = (const int*)d_in[2];
    float*       out  = (float*)d_out;

    bert_span_mean<<<2048, 256, 0, stream>>>(emb, offs, mask, out);
}